// Round 1
// baseline (1267.638 us; speedup 1.0000x reference)
//
#include <hip/hip_runtime.h>

// KMeans distance + argmin:  X (262144 x 128) f32, C (512 x 128) f32
// out = [ distances (512 x 262144) f32 ; assignments (262144) as f32 ]
//
// Strategy (round 1, fp32 correctness baseline):
//  - block = 256 thr = 4 waves, 64 points/block (one per lane), X tile in LDS
//  - each wave owns 128 consecutive k, processed in passes of 16 k
//  - centroid values via wave-uniform scalar loads (SGPR operand of v_fmac)
//  - per-lane top-2 tracking; near-ties (gap < TAU) re-resolved in fp64 by the
//    whole block to make argmin robust against fp32 reassociation noise.

#define NPTS 262144
#define DIM  128
#define KC   512
#define BN   64          // points per block (one per lane)
#define KW   128         // k-range per wave
#define KP   16          // k per pass
#define NPASS (KW / KP)  // 8
#define TAU  2.0e-3f

__device__ float g_csq[KC];

__global__ void csq_kernel(const float* __restrict__ C) {
    int k = blockIdx.x * blockDim.x + threadIdx.x;
    if (k < KC) {
        const float4* row = (const float4*)(C + (size_t)k * DIM);
        float s = 0.f;
#pragma unroll
        for (int i = 0; i < DIM / 4; ++i) {
            float4 v = row[i];
            s += v.x * v.x; s += v.y * v.y; s += v.z * v.z; s += v.w * v.w;
        }
        g_csq[k] = s;
    }
}

__launch_bounds__(256, 4)
__global__ void kmeans_kernel(const float* __restrict__ X,
                              const float* __restrict__ C,
                              float* __restrict__ out) {
    __shared__ float4 Xs[BN * 33];      // 64 rows, stride 33 float4 (132 floats)
    __shared__ float  redv[4 * BN];     // also reused as 256-wide scratch
    __shared__ float  redv2[4 * BN];
    __shared__ int    redi[4 * BN];
    __shared__ int    flagN[8];
    __shared__ int    flagCnt;

    const int tid  = threadIdx.x;
    const int lane = tid & 63;
    const int wave = __builtin_amdgcn_readfirstlane(tid >> 6);
    const int n0   = blockIdx.x * BN;

    float* dist_out   = out;
    float* assign_out = out + (size_t)KC * NPTS;

    if (tid == 0) flagCnt = 0;

    // ---- stage X tile (64 x 128 f32 = 2048 float4), coalesced ----
    const float4* Xg = (const float4*)(X + (size_t)n0 * DIM);
#pragma unroll
    for (int u = 0; u < 8; ++u) {
        int e = tid + u * 256;
        Xs[(e >> 5) * 33 + (e & 31)] = Xg[e];
    }
    __syncthreads();

    // ---- per-lane ||x||^2 from LDS ----
    const float4* xrow = &Xs[lane * 33];
    float xsq = 0.f;
#pragma unroll
    for (int i = 0; i < 32; ++i) {
        float4 v = xrow[i];
        xsq += v.x * v.x; xsq += v.y * v.y; xsq += v.z * v.z; xsq += v.w * v.w;
    }

    float v1 = 3.4e38f, v2 = 3.4e38f;
    int   i1 = 0;

    const int kw0 = wave * KW;
    for (int pass = 0; pass < NPASS; ++pass) {
        const int   kbase = kw0 + pass * KP;
        const float* cbase = C + (size_t)kbase * DIM;   // wave-uniform -> s_load

        float acc[KP];
#pragma unroll
        for (int kk = 0; kk < KP; ++kk) acc[kk] = 0.f;

#pragma unroll 2
        for (int d4 = 0; d4 < 32; ++d4) {
            float4 xv = xrow[d4];                        // ds_read_b128
#pragma unroll
            for (int kk = 0; kk < KP; ++kk) {
                float4 cv = ((const float4*)(cbase + kk * DIM))[d4];  // s_load_dwordx4
                acc[kk] += xv.x * cv.x;
                acc[kk] += xv.y * cv.y;
                acc[kk] += xv.z * cv.z;
                acc[kk] += xv.w * cv.w;
            }
        }

#pragma unroll
        for (int kk = 0; kk < KP; ++kk) {
            int   k  = kbase + kk;
            float dv = g_csq[k] + xsq - 2.0f * acc[kk];
            dist_out[((size_t)k << 18) + n0 + lane] = dv;   // 64-lane contiguous row segment
            bool lt1 = dv < v1;
            float nv2 = lt1 ? v1 : ((dv < v2) ? dv : v2);
            if (lt1) { v1 = dv; i1 = k; }
            v2 = nv2;
        }
    }

    // ---- cross-wave top-2 merge (waves cover ascending k-ranges) ----
    redv[wave * BN + lane]  = v1;
    redv2[wave * BN + lane] = v2;
    redi[wave * BN + lane]  = i1;
    __syncthreads();

    if (tid < BN) {
        float bv1 = redv[tid], bv2 = redv2[tid];
        int   bi1 = redi[tid];
#pragma unroll
        for (int w = 1; w < 4; ++w) {
            float av1 = redv[w * BN + tid], av2 = redv2[w * BN + tid];
            int   ai1 = redi[w * BN + tid];
            if (av1 < bv1 || (av1 == bv1 && ai1 < bi1)) {
                bv2 = fminf(bv1, av2);
                bv1 = av1; bi1 = ai1;
            } else {
                bv2 = fminf(av1, bv2);
            }
        }
        if (bv2 - bv1 < TAU) {
            int slot = atomicAdd(&flagCnt, 1);
            if (slot < 8) flagN[slot] = tid;
        } else {
            assign_out[n0 + tid] = (float)bi1;
        }
    }
    __syncthreads();

    // ---- fp64 refinement of near-ties (rare: ~60 points over whole grid) ----
    int cnt = flagCnt; if (cnt > 8) cnt = 8;
    for (int f = 0; f < cnt; ++f) {
        int fn = flagN[f];
        const float4* xr = &Xs[fn * 33];
        double bv = 1.0e300;
        int    bi = 0;
#pragma unroll
        for (int kk = 0; kk < 2; ++kk) {
            int k = 2 * tid + kk;
            const float4* crow = (const float4*)(C + (size_t)k * DIM);
            double acc = 0.0;
            for (int i = 0; i < 32; ++i) {
                float4 xv = xr[i];
                float4 cv = crow[i];
                double t;
                t = (double)xv.x - (double)cv.x; acc = fma(t, t, acc);
                t = (double)xv.y - (double)cv.y; acc = fma(t, t, acc);
                t = (double)xv.z - (double)cv.z; acc = fma(t, t, acc);
                t = (double)xv.w - (double)cv.w; acc = fma(t, t, acc);
            }
            if (acc < bv) { bv = acc; bi = k; }   // kk ascending -> first-min kept
        }
        redv[tid] = (float)0.0f;   // unused slot silencing; real data below
        // store per-thread candidate
        redv2[tid] = 0.0f;
        // use redv (float) can't hold doubles exactly; serialize via shared arrays:
        // store double as two floats is overkill -- keep (float)bv is NOT exact enough.
        // Instead: lane 0 merge via LDS of (float-pair) -- use static shared doubles:
        {
            __shared__ double rdv[256];
            __shared__ int    rdi[256];
            rdv[tid] = bv; rdi[tid] = bi;
            __syncthreads();
            if (tid == 0) {
                double mbv = rdv[0]; int mbi = rdi[0];
                for (int t = 1; t < 256; ++t) {
                    if (rdv[t] < mbv || (rdv[t] == mbv && rdi[t] < mbi)) {
                        mbv = rdv[t]; mbi = rdi[t];
                    }
                }
                assign_out[n0 + fn] = (float)mbi;
            }
            __syncthreads();
        }
    }
}

extern "C" void kernel_launch(void* const* d_in, const int* in_sizes, int n_in,
                              void* d_out, int out_size, void* d_ws, size_t ws_size,
                              hipStream_t stream) {
    const float* X = (const float*)d_in[0];
    const float* C = (const float*)d_in[1];
    float* out = (float*)d_out;
    (void)in_sizes; (void)n_in; (void)out_size; (void)d_ws; (void)ws_size;
    csq_kernel<<<2, 256, 0, stream>>>(C);
    kmeans_kernel<<<NPTS / BN, 256, 0, stream>>>(X, C, out);
}